// Round 24
// baseline (138.357 us; speedup 1.0000x reference)
//
#include <hip/hip_runtime.h>
#include <hip/hip_bf16.h>

// ---------- types ----------
typedef __attribute__((ext_vector_type(8))) short short8;
typedef __attribute__((ext_vector_type(4))) float f32x4;

__device__ __forceinline__ short tobf(float f) {
  __hip_bfloat16 h = __float2bfloat16(f);
  return *reinterpret_cast<short*>(&h);
}
__device__ __forceinline__ float frombf(short s) {
  unsigned u = ((unsigned)(unsigned short)s) << 16;
  return __uint_as_float(u);
}

// XOR swizzle of the 16B-column index within a 128B LDS row (G4 / T2).
__device__ __forceinline__ int swz(int row) { return (row ^ (row >> 3)) & 7; }

#define GLDS16(gp, lp) __builtin_amdgcn_global_load_lds( \
    (__attribute__((address_space(1))) void*)(gp),       \
    (__attribute__((address_space(3))) void*)(lp), 16, 0, 0)

// raw transcendental: D = 2^S0 (1 inst; inputs bounded, -1e30 -> 0)
__device__ __forceinline__ float exp2raw(float x) {
  float r;
  asm("v_exp_f32 %0, %1" : "=v"(r) : "v"(x));
  return r;
}
// pack 2 f32 -> 2 bf16 in one dword (RNE, same as __float2bfloat16)
__device__ __forceinline__ unsigned cvtpk(float lo, float hi) {
  unsigned r;
  asm("v_cvt_pk_bf16_f32 %0, %1, %2" : "=v"(r) : "v"(lo), "v"(hi));
  return r;
}

// q pre-scale folded into QKV-GEMM epilogue: S = (q*alpha)·k is then in
// log2 domain with the 1/sqrt(64) attention scale included -> attn uses exp2.
#define QSCALE 0.18033688011112042f  // 0.125 * log2(e)

// ---------- fused prep kernel ----------
__global__ __launch_bounds__(256) void prep_k(
    const float* __restrict__ x, short* __restrict__ xb,
    const float* __restrict__ Wqkv, short* __restrict__ WqkvT,
    const float* __restrict__ Wout, short* __restrict__ WoutT,
    float* __restrict__ cost, float* __restrict__ sint) {
  __shared__ float t[64][65];
  const int bx = blockIdx.x, tid = threadIdx.x;
  if (bx < 1024) {
    int base = bx * 4096 + tid * 4;
#pragma unroll
    for (int rep = 0; rep < 4; ++rep) {
      int i = base + rep * 1024;
      float4 v = *(const float4*)(x + i);
      *(short4*)(xb + i) = make_short4(tobf(v.x), tobf(v.y), tobf(v.z), tobf(v.w));
    }
  } else if (bx < 1664) {
    const float* in;
    short* out;
    int C, bb;
    if (bx < 1408) { in = Wqkv; out = WqkvT; C = 1536; bb = bx - 1024; }
    else           { in = Wout; out = WoutT; C = 1024; bb = bx - 1408; }
    const int R = 1024;
    int nc = C >> 6;
    int br = bb / nc, bc = bb % nc;
    int lr = tid >> 6, lc = tid & 63;
#pragma unroll
    for (int j = 0; j < 16; ++j) {
      int r = j * 4 + lr;
      t[r][lc] = in[(size_t)(br * 64 + r) * C + bc * 64 + lc];
    }
    __syncthreads();
#pragma unroll
    for (int j = 0; j < 16; ++j) {
      int r = j * 4 + lr;
      out[(size_t)(bc * 64 + r) * R + br * 64 + lc] = tobf(t[lc][r]);
    }
  } else {
    int t2 = (bx - 1664) * 256 + tid;  // < 65536
    int s = t2 >> 5, f = t2 & 31;
    float inv = __expf(-(float)f * (logf(50000.0f) / 32.0f));
    float a = (float)s * inv;
    cost[t2] = cosf(a);
    sint[t2] = sinf(a);
  }
}

// ---------- GEMM: C[M][N] = A[M][K](bf16) * Bt[N][K](bf16)^T + bias ----------
// 128x64 tiles. MODE 0: QKV proj; RoPE + q-prescale epilogue; q/k tiles ->
// bf16 qkvb; v tiles -> transposed vT directly (fused vtrans). MODE 1: f32 out.
template <int MODE>
__global__ __launch_bounds__(256) void gemm_k(
    const short* __restrict__ A, const short* __restrict__ Bt,
    const float* __restrict__ bias, void* __restrict__ Cout,
    short* __restrict__ vT,
    int M, int N, int K,
    const float* __restrict__ cost, const float* __restrict__ sint) {
  __shared__ short As[128 * 64];  // 16KB
  __shared__ short Bs[64 * 64];   // 8KB
  const int ntile = N >> 6;
  const int bm = blockIdx.x / ntile, bn = blockIdx.x % ntile;
  const int tid = threadIdx.x, w = tid >> 6, l = tid & 63;
  const int c = l & 15, g = l >> 4;
  const int m0 = bm * 128, n0 = bn * 64;

  f32x4 acc[2][4] = {};

  for (int k0 = 0; k0 < K; k0 += 64) {
#pragma unroll
    for (int j = 0; j < 4; ++j) {
      int rb = j * 32 + w * 8;
      int row = rb + (l >> 3);
      int colel = ((l & 7) ^ swz(row)) * 8;  // pre-swizzled source (rule #21)
      GLDS16(A + (size_t)(m0 + row) * K + k0 + colel, &As[rb * 64]);
      if (j < 2) GLDS16(Bt + (size_t)(n0 + row) * K + k0 + colel, &Bs[rb * 64]);
    }
    __syncthreads();
#pragma unroll
    for (int kk = 0; kk < 2; ++kk) {
      short8 af[2], bf[4];
#pragma unroll
      for (int mi = 0; mi < 2; ++mi) {
        int row = w * 32 + mi * 16 + c;
        af[mi] = *(const short8*)&As[row * 64 + ((kk * 4 + g) ^ swz(row)) * 8];
      }
#pragma unroll
      for (int ni = 0; ni < 4; ++ni) {
        int row = ni * 16 + c;
        bf[ni] = *(const short8*)&Bs[row * 64 + ((kk * 4 + g) ^ swz(row)) * 8];
      }
#pragma unroll
      for (int mi = 0; mi < 2; ++mi)
#pragma unroll
        for (int ni = 0; ni < 4; ++ni)
          acc[mi][ni] = __builtin_amdgcn_mfma_f32_16x16x32_bf16(af[mi], bf[ni], acc[mi][ni], 0, 0, 0);
    }
    __syncthreads();
  }

  if (MODE == 0 && n0 >= 1280) {
    // v region: write transposed directly to vT[b*4+hg][64 d][2048 s]
    const int hg = (n0 - 1280) >> 6;
#pragma unroll
    for (int mi = 0; mi < 2; ++mi) {
      int m0r = m0 + w * 32 + mi * 16 + g * 4;  // 4 consecutive rows
      int b = m0r >> 11, s = m0r & 2047;
#pragma unroll
      for (int ni = 0; ni < 4; ++ni) {
        int d = ni * 16 + c;
        float bs = bias[n0 + d];
        short4 o;
        o.x = tobf(acc[mi][ni][0] + bs);
        o.y = tobf(acc[mi][ni][1] + bs);
        o.z = tobf(acc[mi][ni][2] + bs);
        o.w = tobf(acc[mi][ni][3] + bs);
        *(short4*)&vT[(size_t)((b * 4 + hg) * 64 + d) * 2048 + s] = o;
      }
    }
    return;
  }

#pragma unroll
  for (int mi = 0; mi < 2; ++mi)
#pragma unroll
    for (int r = 0; r < 4; ++r) {
      int m = m0 + w * 32 + mi * 16 + g * 4 + r;
      int s = m & 2047;
#pragma unroll
      for (int ni = 0; ni < 4; ++ni) {
        int n = n0 + ni * 16 + c;
        float v = acc[mi][ni][r] + bias[n];
        if (MODE == 0) {
          // q or k region (n < 1280 guaranteed here): apply RoPE
          int d = n & 63, f = d & 31;
          float cs = cost[s * 32 + f], sn = sint[s * 32 + f];
          float partner = acc[mi][ni ^ 2][r] + bias[n ^ 32];
          v = (d < 32) ? (v * cs - partner * sn) : (v * cs + partner * sn);
          if (n < 1024) v *= QSCALE;  // q prescale (commutes with rotation)
          ((short*)Cout)[(size_t)m * N + n] = tobf(v);
        } else {
          ((float*)Cout)[(size_t)m * N + n] = v;
        }
      }
    }
}

// ---------- flash attention (causal, GQA): 4 Q-SETS PER WAVE ----------
// QBLK=512: 8 waves x 64 q-rows (4 sets of 16) -> the same 16 bk/bv LDS
// fragment reads feed 64 MFMA (R23 measured LDS as the dominant pipe: all
// 8 waves read identical fragments, so amortize over 4 sets instead of 2).
// Pair (qtB=3-p, qtA=p): exactly 40 k-tiles; 4 quarters of 10 -> grid 256
// = 1 block/CU, 5 super-barriers (2 cores per span, 6-buffer rotation,
// counted vmcnt(4)). Lane-partial lrun, raw v_exp_f32, cvt_pk pack.
__global__ __launch_bounds__(512) void attn_k(const short* __restrict__ qkv,
                                              const short* __restrict__ vT,
                                              short* __restrict__ pacc,
                                              float* __restrict__ plrun) {
  __shared__ short Ks6[6][64 * 64];  // 48KB
  __shared__ short Vt6[6][64 * 64];  // 48KB
  __shared__ short Ps[8][16 * 64];   // 16KB per-wave P tiles

  const int bx = blockIdx.x;
  const int bh = bx & 31;
  const int rest = bx >> 5;          // 0..7
  const int p = rest & 1;            // pair 0..1
  const int quarter = rest >> 1;     // 0..3
  const int qtB = 3 - p, qtA = p;
  const int sB = 8 * (qtB + 1);      // 32 or 24
  const int start = quarter * 10;
  const int end = start + 10;
  const int b = bh >> 4, h = bh & 15, hg = h >> 2;
  const int tid = threadIdx.x, w = tid >> 6, l = tid & 63;
  const int c = l & 15, g = l >> 4;
  const size_t rowbase = (size_t)(b * 2048) * 1536;

  // staging: each wave stages 8 rows (1 GLDS16 per tile per thread)
  const int srow = w * 8 + (l >> 3);
  const int scol = ((l & 7) ^ swz(srow)) * 8;
  const size_t koff = (size_t)srow * 1536 + scol;
  const size_t voff = (size_t)srow * 2048 + scol;
  const int ldsoff = (w * 8) * 64;   // wave-uniform LDS base
  const short* kbase = qkv + rowbase + 1024 + hg * 64;
  const short* vbase_p = vT + (size_t)((b * 4 + hg) * 64) * 2048;

#define KTOF(i) (((i) < sB) ? (i) : ((i) - sB))

  // ---- prologue: issue tiles start..start+3 ----
#pragma unroll
  for (int t = 0; t < 4; ++t) {
    int idx = start + t;
    int kt0 = KTOF(idx);
    int bf_ = idx % 6;
    GLDS16(kbase + (size_t)kt0 * 98304 + koff, &Ks6[bf_][ldsoff]);
    GLDS16(vbase_p + kt0 * 64 + voff, &Vt6[bf_][ldsoff]);
  }
  asm volatile("s_waitcnt vmcnt(4)" ::: "memory");  // tiles start,start+1 landed
  __builtin_amdgcn_s_barrier();
  __builtin_amdgcn_sched_barrier(0);

  f32x4 acco[4][4] = {};
  float lrun[4] = {0.f, 0.f, 0.f, 0.f};  // LANE-PARTIAL; reduced at store
  short* Pw = &Ps[w][0];
  short8 aq[4][2];

  // Q fragments for qtB: q = qtB*512 + w*64 + set*16 + c
#pragma unroll
  for (int set = 0; set < 4; ++set)
#pragma unroll
    for (int kk = 0; kk < 2; ++kk)
      aq[set][kk] = *(const short8*)(qkv + rowbase +
          (size_t)(qtB * 512 + w * 64 + set * 16 + c) * 1536 + h * 64 + kk * 32 + g * 8);

// one k-tile core: shared bk/bv reads feed 4 q-sets (QK, softmax, PV per set)
#define CORE(qtc, TI)                                                           \
  {                                                                             \
    const int kt_ = KTOF(TI);                                                   \
    const int bf_ = (TI) % 6;                                                   \
    short8 bk[2][4], bv[2][4];                                                  \
    _Pragma("unroll") for (int kk = 0; kk < 2; ++kk)                            \
      _Pragma("unroll") for (int nb = 0; nb < 4; ++nb) {                        \
        int row = nb * 16 + c;                                                  \
        int cs_ = ((kk * 4 + g) ^ swz(row)) * 8;                                \
        bk[kk][nb] = *(const short8*)&Ks6[bf_][row * 64 + cs_];                 \
        bv[kk][nb] = *(const short8*)&Vt6[bf_][row * 64 + cs_];                 \
      }                                                                         \
    const bool diag_ = (kt_ >= 8 * (qtc));                                      \
    _Pragma("unroll") for (int set = 0; set < 4; ++set) {                       \
      f32x4 sfr[4] = {};                                                        \
      __builtin_amdgcn_s_setprio(1);                                            \
      _Pragma("unroll") for (int kk = 0; kk < 2; ++kk)                          \
        _Pragma("unroll") for (int nb = 0; nb < 4; ++nb)                        \
          sfr[nb] = __builtin_amdgcn_mfma_f32_16x16x32_bf16(                    \
              bk[kk][nb], aq[set][kk], sfr[nb], 0, 0, 0);                       \
      __builtin_amdgcn_s_setprio(0);                                            \
      if (diag_) {                                                              \
        int qg = (qtc)*512 + w * 64 + set * 16 + c;                             \
        _Pragma("unroll") for (int nb = 0; nb < 4; ++nb)                        \
          _Pragma("unroll") for (int r = 0; r < 4; ++r)                         \
            if (kt_ * 64 + nb * 16 + g * 4 + r > qg) sfr[nb][r] = -1e30f;       \
      }                                                                         \
      float rsn[4];                                                             \
      _Pragma("unroll") for (int nb = 0; nb < 4; ++nb) {                        \
        float p0 = exp2raw(sfr[nb][0]);                                         \
        float p1 = exp2raw(sfr[nb][1]);                                         \
        float p2 = exp2raw(sfr[nb][2]);                                         \
        float p3 = exp2raw(sfr[nb][3]);                                         \
        sfr[nb][0] = p0; sfr[nb][1] = p1;                                       \
        sfr[nb][2] = p2; sfr[nb][3] = p3;                                       \
        rsn[nb] = (p0 + p1) + (p2 + p3);                                        \
      }                                                                         \
      lrun[set] += (rsn[0] + rsn[1]) + (rsn[2] + rsn[3]);                       \
      _Pragma("unroll") for (int nb = 0; nb < 4; ++nb) {                        \
        unsigned d0 = cvtpk(sfr[nb][0], sfr[nb][1]);                            \
        unsigned d1 = cvtpk(sfr[nb][2], sfr[nb][3]);                            \
        int pslot = (nb * 2 + (g >> 1)) ^ swz(c);                               \
        int2 pq2 = make_int2((int)d0, (int)d1);                                 \
        *(int2*)&Pw[c * 64 + pslot * 8 + (g & 1) * 4] = pq2;                    \
      }                                                                         \
      __builtin_amdgcn_s_setprio(1);                                            \
      _Pragma("unroll") for (int kk = 0; kk < 2; ++kk) {                        \
        short8 ap = *(const short8*)&Pw[c * 64 + (((kk * 4 + g) ^ swz(c)) * 8)];\
        _Pragma("unroll") for (int nb = 0; nb < 4; ++nb)                        \
          acco[set][nb] = __builtin_amdgcn_mfma_f32_16x16x32_bf16(              \
              ap, bv[kk][nb], acco[set][nb], 0, 0, 0);                          \
      }                                                                         \
      __builtin_amdgcn_s_setprio(0);                                            \
    }                                                                           \
  }

// super-iter: prefetch tiles i+4,i+5 (buffers i-2,i-1 mod 6: retired), then
// two cores, then counted-vmcnt barrier (newest 4 loads stay in flight)
#define SUPER(qtc)                                                              \
  {                                                                             \
    const bool pf_ = (i + 4 < end);                                             \
    if (pf_) {                                                                  \
      int ta = KTOF(i + 4), tb = KTOF(i + 5);                                   \
      int ba = (i + 4) % 6, bb2 = (i + 5) % 6;                                  \
      GLDS16(kbase + (size_t)ta * 98304 + koff, &Ks6[ba][ldsoff]);              \
      GLDS16(vbase_p + ta * 64 + voff, &Vt6[ba][ldsoff]);                       \
      GLDS16(kbase + (size_t)tb * 98304 + koff, &Ks6[bb2][ldsoff]);             \
      GLDS16(vbase_p + tb * 64 + voff, &Vt6[bb2][ldsoff]);                      \
    }                                                                           \
    CORE(qtc, i);                                                               \
    CORE(qtc, i + 1);                                                           \
    if (pf_) asm volatile("s_waitcnt vmcnt(4)" ::: "memory");                   \
    else     asm volatile("s_waitcnt vmcnt(0)" ::: "memory");                   \
    __builtin_amdgcn_s_barrier();                                               \
    __builtin_amdgcn_sched_barrier(0);                                          \
  }

#define STORE_PARTIAL(slot)                                                     \
  {                                                                             \
    int sidx = ((bh * 2 + p) * 4 + quarter) * 2 + (slot);                       \
    size_t pb = (size_t)sidx * 32768;                                           \
    _Pragma("unroll") for (int set = 0; set < 4; ++set) {                       \
      _Pragma("unroll") for (int nb = 0; nb < 4; ++nb)                          \
        _Pragma("unroll") for (int r = 0; r < 4; ++r) {                         \
          int row = w * 64 + set * 16 + g * 4 + r;                              \
          pacc[pb + row * 64 + nb * 16 + c] = tobf(acco[set][nb][r]);           \
          acco[set][nb][r] = 0.f;                                               \
        }                                                                       \
      float lr_ = lrun[set];                                                    \
      lr_ += __shfl_xor(lr_, 16, 64);                                           \
      lr_ += __shfl_xor(lr_, 32, 64);  /* full row sum over 4 g-lanes */        \
      if (g == 0) plrun[sidx * 512 + w * 64 + set * 16 + c] = lr_;              \
      lrun[set] = 0.f;                                                          \
    }                                                                           \
  }

  int i = start;
  const int endB = (end < sB) ? end : sB;  // crossings land on even offsets
  for (; i < endB; i += 2) SUPER(qtB);
  STORE_PARTIAL(0);

  // swap Q fragments to qtA (reuses aq registers; qtB frags dead)
#pragma unroll
  for (int set = 0; set < 4; ++set)
#pragma unroll
    for (int kk = 0; kk < 2; ++kk)
      aq[set][kk] = *(const short8*)(qkv + rowbase +
          (size_t)(qtA * 512 + w * 64 + set * 16 + c) * 1536 + h * 64 + kk * 32 + g * 8);

  for (; i < end; i += 2) SUPER(qtA);
  STORE_PARTIAL(1);

#undef CORE
#undef SUPER
#undef STORE_PARTIAL
#undef KTOF
}

// ---------- combine: sum 4 quarter-partials, normalize ----------
__global__ __launch_bounds__(256) void combine_k(const short* __restrict__ pacc,
                                                 const float* __restrict__ plrun,
                                                 short* __restrict__ attnb) {
  int e = blockIdx.x * 256 + threadIdx.x;  // 0..524287
  int d8 = e & 7;
  int t = e >> 3;
  int row = t & 511;                 // 0..511 within q-tile of 512
  int t2 = t >> 9;
  int qt = t2 & 3;                   // q-tile of 512 rows
  int bh = t2 >> 2;
  int pair = (qt == 3 || qt == 0) ? 0 : 1;
  int slot = (qt >= 2) ? 0 : 1;
  float acc[8] = {};
  float lsum = 0.f;
#pragma unroll
  for (int q = 0; q < 4; ++q) {
    int sidx = ((bh * 2 + pair) * 4 + q) * 2 + slot;
    short8 a = *(const short8*)(pacc + (size_t)sidx * 32768 + row * 64 + d8 * 8);
#pragma unroll
    for (int k = 0; k < 8; ++k) acc[k] += frombf(a[k]);
    lsum += plrun[sidx * 512 + row];
  }
  float li = 1.0f / lsum;
  int b = bh >> 4, h = bh & 15;
  int m = b * 2048 + qt * 512 + row;
  int n = h * 64 + d8 * 8;
  short8 o;
#pragma unroll
  for (int k = 0; k < 8; ++k) o[k] = tobf(acc[k] * li);
  *(short8*)(attnb + (size_t)m * 1024 + n) = o;
}

// ---------- launch ----------
extern "C" void kernel_launch(void* const* d_in, const int* in_sizes, int n_in,
                              void* d_out, int out_size, void* d_ws, size_t ws_size,
                              hipStream_t stream) {
  const float* x    = (const float*)d_in[0];
  const float* Wqkv = (const float*)d_in[1];
  const float* bqkv = (const float*)d_in[2];
  const float* Wout = (const float*)d_in[3];
  const float* bout = (const float*)d_in[4];

  char* ws = (char*)d_ws;
  // Compact aliased layout, total 51,380,224 B (proven-safe R19-R23):
  //  [0, 33.55M)        pacc  [512][512][64] bf16 = 33,554,432 B exactly
  //    [0, 8.39M)         xb     (gemm0-only; dead before attn_k writes pacc)
  //    [8.39M, 11.53M)    WqkvT  (gemm0-only)
  //    [11.53M, 11.80M)   cost   (gemm0-only)
  //    [11.80M, 12.06M)   sint   (gemm0-only)
  //  [33.55M, 35.65M)   WoutT (live prep_k -> gemm1)
  //  [35.65M, 48.23M)   qkvb  (gemm0 -> attn_k)
  //    [35.65M, 44.04M)   attnb (aliases qkvb: written by combine_k AFTER
  //                              qkvb's last read in attn_k; read by gemm1)
  //  [48.23M, 50.33M)   vTb   (gemm0 -> attn_k)
  //  [50.33M, 51.38M)   plrun [512][512] f32 = 1,048,576 B exactly
  short* pacc  = (short*)(ws + 0);
  short* xb    = (short*)(ws + 0);
  short* WqkvT = (short*)(ws + 8388608);
  float* cost  = (float*)(ws + 11534336);
  float* sint  = (float*)(ws + 11796480);
  short* WoutT = (short*)(ws + 33554432);
  short* qkvb  = (short*)(ws + 35651584);
  short* attnb = (short*)(ws + 35651584);
  short* vTb   = (short*)(ws + 48234496);
  float* plrun = (float*)(ws + 50331648);

  prep_k<<<1920, 256, 0, stream>>>(x, xb, Wqkv, WqkvT, Wout, WoutT, cost, sint);
  gemm_k<0><<<768, 256, 0, stream>>>(xb, WqkvT, bqkv, (void*)qkvb, vTb, 4096, 1536, 1024, cost, sint);
  attn_k<<<256, 512, 0, stream>>>(qkvb, vTb, pacc, plrun);
  combine_k<<<2048, 256, 0, stream>>>(pacc, plrun, attnb);
  gemm_k<1><<<512, 256, 0, stream>>>(attnb, WoutT, bout, d_out, nullptr, 4096, 1024, 1024, cost, sint);
}

// Round 25
// 88.997 us; speedup vs baseline: 1.5546x; 1.5546x over previous
//
#include <hip/hip_runtime.h>
#include <hip/hip_bf16.h>

// ---------- types ----------
typedef __attribute__((ext_vector_type(8))) short short8;
typedef __attribute__((ext_vector_type(4))) float f32x4;

__device__ __forceinline__ short tobf(float f) {
  __hip_bfloat16 h = __float2bfloat16(f);
  return *reinterpret_cast<short*>(&h);
}
__device__ __forceinline__ float frombf(short s) {
  unsigned u = ((unsigned)(unsigned short)s) << 16;
  return __uint_as_float(u);
}

// XOR swizzle of the 16B-column index within a 128B LDS row (G4 / T2).
__device__ __forceinline__ int swz(int row) { return (row ^ (row >> 3)) & 7; }

#define GLDS16(gp, lp) __builtin_amdgcn_global_load_lds( \
    (__attribute__((address_space(1))) void*)(gp),       \
    (__attribute__((address_space(3))) void*)(lp), 16, 0, 0)

// raw transcendental: D = 2^S0 (1 inst; inputs bounded, -1e30 -> 0)
__device__ __forceinline__ float exp2raw(float x) {
  float r;
  asm("v_exp_f32 %0, %1" : "=v"(r) : "v"(x));
  return r;
}
// pack 2 f32 -> 2 bf16 in one dword (RNE, same as __float2bfloat16)
__device__ __forceinline__ unsigned cvtpk(float lo, float hi) {
  unsigned r;
  asm("v_cvt_pk_bf16_f32 %0, %1, %2" : "=v"(r) : "v"(lo), "v"(hi));
  return r;
}

// q pre-scale folded into QKV-GEMM epilogue: S = (q*alpha)·k is then in
// log2 domain with the 1/sqrt(64) attention scale included -> attn uses exp2.
#define QSCALE 0.18033688011112042f  // 0.125 * log2(e)

// ---------- fused prep kernel ----------
__global__ __launch_bounds__(256) void prep_k(
    const float* __restrict__ x, short* __restrict__ xb,
    const float* __restrict__ Wqkv, short* __restrict__ WqkvT,
    const float* __restrict__ Wout, short* __restrict__ WoutT,
    float* __restrict__ cost, float* __restrict__ sint) {
  __shared__ float t[64][65];
  const int bx = blockIdx.x, tid = threadIdx.x;
  if (bx < 1024) {
    int base = bx * 4096 + tid * 4;
#pragma unroll
    for (int rep = 0; rep < 4; ++rep) {
      int i = base + rep * 1024;
      float4 v = *(const float4*)(x + i);
      *(short4*)(xb + i) = make_short4(tobf(v.x), tobf(v.y), tobf(v.z), tobf(v.w));
    }
  } else if (bx < 1664) {
    const float* in;
    short* out;
    int C, bb;
    if (bx < 1408) { in = Wqkv; out = WqkvT; C = 1536; bb = bx - 1024; }
    else           { in = Wout; out = WoutT; C = 1024; bb = bx - 1408; }
    const int R = 1024;
    int nc = C >> 6;
    int br = bb / nc, bc = bb % nc;
    int lr = tid >> 6, lc = tid & 63;
#pragma unroll
    for (int j = 0; j < 16; ++j) {
      int r = j * 4 + lr;
      t[r][lc] = in[(size_t)(br * 64 + r) * C + bc * 64 + lc];
    }
    __syncthreads();
#pragma unroll
    for (int j = 0; j < 16; ++j) {
      int r = j * 4 + lr;
      out[(size_t)(bc * 64 + r) * R + br * 64 + lc] = tobf(t[lc][r]);
    }
  } else {
    int t2 = (bx - 1664) * 256 + tid;  // < 65536
    int s = t2 >> 5, f = t2 & 31;
    float inv = __expf(-(float)f * (logf(50000.0f) / 32.0f));
    float a = (float)s * inv;
    cost[t2] = cosf(a);
    sint[t2] = sinf(a);
  }
}

// ---------- GEMM: C[M][N] = A[M][K](bf16) * Bt[N][K](bf16)^T + bias ----------
// 128x64 tiles. MODE 0: QKV proj; RoPE + q-prescale epilogue; q/k tiles ->
// bf16 qkvb; v tiles -> transposed vT directly (fused vtrans). MODE 1: f32 out.
template <int MODE>
__global__ __launch_bounds__(256) void gemm_k(
    const short* __restrict__ A, const short* __restrict__ Bt,
    const float* __restrict__ bias, void* __restrict__ Cout,
    short* __restrict__ vT,
    int M, int N, int K,
    const float* __restrict__ cost, const float* __restrict__ sint) {
  __shared__ short As[128 * 64];  // 16KB
  __shared__ short Bs[64 * 64];   // 8KB
  const int ntile = N >> 6;
  const int bm = blockIdx.x / ntile, bn = blockIdx.x % ntile;
  const int tid = threadIdx.x, w = tid >> 6, l = tid & 63;
  const int c = l & 15, g = l >> 4;
  const int m0 = bm * 128, n0 = bn * 64;

  f32x4 acc[2][4] = {};

  for (int k0 = 0; k0 < K; k0 += 64) {
#pragma unroll
    for (int j = 0; j < 4; ++j) {
      int rb = j * 32 + w * 8;
      int row = rb + (l >> 3);
      int colel = ((l & 7) ^ swz(row)) * 8;  // pre-swizzled source (rule #21)
      GLDS16(A + (size_t)(m0 + row) * K + k0 + colel, &As[rb * 64]);
      if (j < 2) GLDS16(Bt + (size_t)(n0 + row) * K + k0 + colel, &Bs[rb * 64]);
    }
    __syncthreads();
#pragma unroll
    for (int kk = 0; kk < 2; ++kk) {
      short8 af[2], bf[4];
#pragma unroll
      for (int mi = 0; mi < 2; ++mi) {
        int row = w * 32 + mi * 16 + c;
        af[mi] = *(const short8*)&As[row * 64 + ((kk * 4 + g) ^ swz(row)) * 8];
      }
#pragma unroll
      for (int ni = 0; ni < 4; ++ni) {
        int row = ni * 16 + c;
        bf[ni] = *(const short8*)&Bs[row * 64 + ((kk * 4 + g) ^ swz(row)) * 8];
      }
#pragma unroll
      for (int mi = 0; mi < 2; ++mi)
#pragma unroll
        for (int ni = 0; ni < 4; ++ni)
          acc[mi][ni] = __builtin_amdgcn_mfma_f32_16x16x32_bf16(af[mi], bf[ni], acc[mi][ni], 0, 0, 0);
    }
    __syncthreads();
  }

  if (MODE == 0 && n0 >= 1280) {
    // v region: write transposed directly to vT[b*4+hg][64 d][2048 s]
    const int hg = (n0 - 1280) >> 6;
#pragma unroll
    for (int mi = 0; mi < 2; ++mi) {
      int m0r = m0 + w * 32 + mi * 16 + g * 4;  // 4 consecutive rows
      int b = m0r >> 11, s = m0r & 2047;
#pragma unroll
      for (int ni = 0; ni < 4; ++ni) {
        int d = ni * 16 + c;
        float bs = bias[n0 + d];
        short4 o;
        o.x = tobf(acc[mi][ni][0] + bs);
        o.y = tobf(acc[mi][ni][1] + bs);
        o.z = tobf(acc[mi][ni][2] + bs);
        o.w = tobf(acc[mi][ni][3] + bs);
        *(short4*)&vT[(size_t)((b * 4 + hg) * 64 + d) * 2048 + s] = o;
      }
    }
    return;
  }

#pragma unroll
  for (int mi = 0; mi < 2; ++mi)
#pragma unroll
    for (int r = 0; r < 4; ++r) {
      int m = m0 + w * 32 + mi * 16 + g * 4 + r;
      int s = m & 2047;
#pragma unroll
      for (int ni = 0; ni < 4; ++ni) {
        int n = n0 + ni * 16 + c;
        float v = acc[mi][ni][r] + bias[n];
        if (MODE == 0) {
          // q or k region (n < 1280 guaranteed here): apply RoPE
          int d = n & 63, f = d & 31;
          float cs = cost[s * 32 + f], sn = sint[s * 32 + f];
          float partner = acc[mi][ni ^ 2][r] + bias[n ^ 32];
          v = (d < 32) ? (v * cs - partner * sn) : (v * cs + partner * sn);
          if (n < 1024) v *= QSCALE;  // q prescale (commutes with rotation)
          ((short*)Cout)[(size_t)m * N + n] = tobf(v);
        } else {
          ((float*)Cout)[(size_t)m * N + n] = v;
        }
      }
    }
}

// ---------- flash attention (causal, GQA): 2 K-TILES PER BARRIER ----------
// R21 base (QBLK=256, 8 waves x 32 q-rows, grid 256 = 1 block/CU, pair
// (qtB=7-p, qtA=p) split in 2 halves of 18 tiles) with SUPER-ITERS: each
// barrier span consumes 2 k-tiles (core(i); core(i+1)) -> 9 barriers/block
// instead of 18, and core(i+1)'s QK overlaps core(i)'s softmax/PV (ILP).
// 6-buffer rotation (buf = i%6): prefetch at span top writes buffer classes
// i-2,i-1 (retired >=1 barrier ago), never live {i,i+1} or next {i+2,i+3}.
// Counted vmcnt(4) at the barrier keeps the newest 2-tile batch in flight.
// (R24's 4-q-set variant spilled to scratch: 2 sets is the VGPR equilibrium.)
__global__ __launch_bounds__(512) void attn_k(const short* __restrict__ qkv,
                                              const short* __restrict__ vT,
                                              short* __restrict__ pacc,
                                              float* __restrict__ plrun) {
  __shared__ short Ks6[6][64 * 64];  // 48KB
  __shared__ short Vt6[6][64 * 64];  // 48KB
  __shared__ short Ps[8][16 * 64];   // 16KB per-wave P tiles

  const int bx = blockIdx.x;
  const int bh = bx & 31;
  const int rest = bx >> 5;          // 0..7
  const int p = rest & 3;            // pair 0..3
  const int half = rest >> 2;        // 0 or 1
  const int qtB = 7 - p, qtA = p;
  const int sB = 32 - 4 * p;         // k-tiles in qtB's causal range (>= 20, even)
  const int start = half * 18;
  const int end = start + 18;
  const int b = bh >> 4, h = bh & 15, hg = h >> 2;
  const int tid = threadIdx.x, w = tid >> 6, l = tid & 63;
  const int c = l & 15, g = l >> 4;
  const size_t rowbase = (size_t)(b * 2048) * 1536;

  // staging: each wave stages 8 rows (1 GLDS16 per tile per thread)
  const int srow = w * 8 + (l >> 3);
  const int scol = ((l & 7) ^ swz(srow)) * 8;
  const size_t koff = (size_t)srow * 1536 + scol;
  const size_t voff = (size_t)srow * 2048 + scol;
  const int ldsoff = (w * 8) * 64;   // wave-uniform LDS base
  const short* kbase = qkv + rowbase + 1024 + hg * 64;
  const short* vbase_p = vT + (size_t)((b * 4 + hg) * 64) * 2048;

#define KTOF(i) (((i) < sB) ? (i) : ((i) - sB))

  // ---- prologue: issue tiles start..start+3 (segments have >= 18 tiles) ----
#pragma unroll
  for (int t = 0; t < 4; ++t) {
    int idx = start + t;
    int kt0 = KTOF(idx);
    int bf_ = idx % 6;
    GLDS16(kbase + (size_t)kt0 * 98304 + koff, &Ks6[bf_][ldsoff]);
    GLDS16(vbase_p + kt0 * 64 + voff, &Vt6[bf_][ldsoff]);
  }
  asm volatile("s_waitcnt vmcnt(4)" ::: "memory");  // tiles start,start+1 landed
  __builtin_amdgcn_s_barrier();
  __builtin_amdgcn_sched_barrier(0);

  f32x4 acco[2][4] = {};
  float lrun[2] = {0.f, 0.f};  // LANE-PARTIAL (own 16 k-slots); reduced at store
  short* Pw = &Ps[w][0];
  short8 aq[2][2];

  // Q fragments for qtB: q = qtB*256 + w*32 + set*16 + c
#pragma unroll
  for (int set = 0; set < 2; ++set)
#pragma unroll
    for (int kk = 0; kk < 2; ++kk)
      aq[set][kk] = *(const short8*)(qkv + rowbase +
          (size_t)(qtB * 256 + w * 32 + set * 16 + c) * 1536 + h * 64 + kk * 32 + g * 8);

// one k-tile core: QK -> mask -> exp -> pack -> PV (no sync; buffer TI%6)
#define CORE(qtc, TI)                                                           \
  {                                                                             \
    const int kt_ = KTOF(TI);                                                   \
    const int bf_ = (TI) % 6;                                                   \
    short8 bk[2][4];                                                            \
    _Pragma("unroll") for (int kk = 0; kk < 2; ++kk)                            \
      _Pragma("unroll") for (int nb = 0; nb < 4; ++nb) {                        \
        int row = nb * 16 + c;                                                  \
        bk[kk][nb] = *(const short8*)&Ks6[bf_][row * 64 + ((kk * 4 + g) ^ swz(row)) * 8]; \
      }                                                                         \
    f32x4 sfr[2][4] = {};                                                       \
    __builtin_amdgcn_s_setprio(1);                                              \
    _Pragma("unroll") for (int set = 0; set < 2; ++set)                         \
      _Pragma("unroll") for (int kk = 0; kk < 2; ++kk)                          \
        _Pragma("unroll") for (int nb = 0; nb < 4; ++nb)                        \
          sfr[set][nb] = __builtin_amdgcn_mfma_f32_16x16x32_bf16(               \
              bk[kk][nb], aq[set][kk], sfr[set][nb], 0, 0, 0);                  \
    __builtin_amdgcn_s_setprio(0);                                              \
    short8 bv[2][4];                                                            \
    _Pragma("unroll") for (int kk = 0; kk < 2; ++kk)                            \
      _Pragma("unroll") for (int nb = 0; nb < 4; ++nb) {                        \
        int row = nb * 16 + c;                                                  \
        bv[kk][nb] = *(const short8*)&Vt6[bf_][row * 64 + ((kk * 4 + g) ^ swz(row)) * 8]; \
      }                                                                         \
    if (kt_ >= 4 * (qtc)) {  /* tiles intersecting the diagonal band */         \
      _Pragma("unroll") for (int set = 0; set < 2; ++set) {                     \
        int qg = (qtc)*256 + w * 32 + set * 16 + c;                             \
        _Pragma("unroll") for (int nb = 0; nb < 4; ++nb)                        \
          _Pragma("unroll") for (int r = 0; r < 4; ++r)                         \
            if (kt_ * 64 + nb * 16 + g * 4 + r > qg) sfr[set][nb][r] = -1e30f;  \
      }                                                                         \
    }                                                                           \
    _Pragma("unroll") for (int set = 0; set < 2; ++set) {                       \
      float rsn[4];                                                             \
      _Pragma("unroll") for (int nb = 0; nb < 4; ++nb) {                        \
        float p0 = exp2raw(sfr[set][nb][0]);                                    \
        float p1 = exp2raw(sfr[set][nb][1]);                                    \
        float p2 = exp2raw(sfr[set][nb][2]);                                    \
        float p3 = exp2raw(sfr[set][nb][3]);                                    \
        sfr[set][nb][0] = p0; sfr[set][nb][1] = p1;                             \
        sfr[set][nb][2] = p2; sfr[set][nb][3] = p3;                             \
        rsn[nb] = (p0 + p1) + (p2 + p3);                                        \
      }                                                                         \
      lrun[set] += (rsn[0] + rsn[1]) + (rsn[2] + rsn[3]);                       \
      _Pragma("unroll") for (int nb = 0; nb < 4; ++nb) {                        \
        unsigned d0 = cvtpk(sfr[set][nb][0], sfr[set][nb][1]);                  \
        unsigned d1 = cvtpk(sfr[set][nb][2], sfr[set][nb][3]);                  \
        int pslot = (nb * 2 + (g >> 1)) ^ swz(c);                               \
        int2 pq2 = make_int2((int)d0, (int)d1);                                 \
        *(int2*)&Pw[c * 64 + pslot * 8 + (g & 1) * 4] = pq2;                    \
      }                                                                         \
      __builtin_amdgcn_s_setprio(1);                                            \
      _Pragma("unroll") for (int kk = 0; kk < 2; ++kk) {                        \
        short8 ap = *(const short8*)&Pw[c * 64 + (((kk * 4 + g) ^ swz(c)) * 8)];\
        _Pragma("unroll") for (int nb = 0; nb < 4; ++nb)                        \
          acco[set][nb] = __builtin_amdgcn_mfma_f32_16x16x32_bf16(              \
              ap, bv[kk][nb], acco[set][nb], 0, 0, 0);                          \
      }                                                                         \
      __builtin_amdgcn_s_setprio(0);                                            \
    }                                                                           \
  }

// super-iter: prefetch tiles i+4,i+5 (buffers i-2,i-1 mod 6: retired), then
// two cores, then counted-vmcnt barrier (newest 4 loads stay in flight)
#define SUPER(qtc)                                                              \
  {                                                                             \
    const bool pf_ = (i + 4 < end);                                             \
    if (pf_) {                                                                  \
      int ta = KTOF(i + 4), tb = KTOF(i + 5);                                   \
      int ba = (i + 4) % 6, bb2 = (i + 5) % 6;                                  \
      GLDS16(kbase + (size_t)ta * 98304 + koff, &Ks6[ba][ldsoff]);              \
      GLDS16(vbase_p + ta * 64 + voff, &Vt6[ba][ldsoff]);                       \
      GLDS16(kbase + (size_t)tb * 98304 + koff, &Ks6[bb2][ldsoff]);             \
      GLDS16(vbase_p + tb * 64 + voff, &Vt6[bb2][ldsoff]);                      \
    }                                                                           \
    CORE(qtc, i);                                                               \
    CORE(qtc, i + 1);                                                           \
    if (pf_) asm volatile("s_waitcnt vmcnt(4)" ::: "memory");                   \
    else     asm volatile("s_waitcnt vmcnt(0)" ::: "memory");                   \
    __builtin_amdgcn_s_barrier();                                               \
    __builtin_amdgcn_sched_barrier(0);                                          \
  }

#define STORE_PARTIAL(slot)                                                     \
  {                                                                             \
    int sidx = ((bh * 4 + p) * 2 + half) * 2 + (slot);                          \
    size_t pb = (size_t)sidx * 16384;                                           \
    _Pragma("unroll") for (int set = 0; set < 2; ++set) {                       \
      _Pragma("unroll") for (int nb = 0; nb < 4; ++nb)                          \
        _Pragma("unroll") for (int r = 0; r < 4; ++r) {                         \
          int row = w * 32 + set * 16 + g * 4 + r;                              \
          pacc[pb + row * 64 + nb * 16 + c] = tobf(acco[set][nb][r]);           \
          acco[set][nb][r] = 0.f;                                               \
        }                                                                       \
      float lr_ = lrun[set];                                                    \
      lr_ += __shfl_xor(lr_, 16, 64);                                           \
      lr_ += __shfl_xor(lr_, 32, 64);  /* full row sum over 4 g-lanes */        \
      if (g == 0) plrun[sidx * 256 + w * 32 + set * 16 + c] = lr_;              \
      lrun[set] = 0.f;                                                          \
    }                                                                           \
  }

  int i = start;
  const int endB = (end < sB) ? end : sB;  // segment lengths are even
  for (; i < endB; i += 2) SUPER(qtB);
  STORE_PARTIAL(0);

  // swap Q fragments to qtA (reuses aq registers; qtB frags dead)
#pragma unroll
  for (int set = 0; set < 2; ++set)
#pragma unroll
    for (int kk = 0; kk < 2; ++kk)
      aq[set][kk] = *(const short8*)(qkv + rowbase +
          (size_t)(qtA * 256 + w * 32 + set * 16 + c) * 1536 + h * 64 + kk * 32 + g * 8);

  for (; i < end; i += 2) SUPER(qtA);
  STORE_PARTIAL(1);

#undef CORE
#undef SUPER
#undef STORE_PARTIAL
#undef KTOF
}

// ---------- combine: sum 2 half-partials, normalize ----------
__global__ __launch_bounds__(256) void combine_k(const short* __restrict__ pacc,
                                                 const float* __restrict__ plrun,
                                                 short* __restrict__ attnb) {
  int e = blockIdx.x * 256 + threadIdx.x;  // 0..524287
  int d8 = e & 7;
  int t = e >> 3;
  int row = t & 255;                 // 0..255 within q-tile
  int t2 = t >> 8;
  int qt = t2 & 7;                   // q-tile of 256 rows
  int bh = t2 >> 3;
  int p = (qt < 7 - qt) ? qt : 7 - qt;
  int slot = (qt >= 4) ? 0 : 1;
  float acc[8] = {};
  float lsum = 0.f;
#pragma unroll
  for (int half = 0; half < 2; ++half) {
    int sidx = ((bh * 4 + p) * 2 + half) * 2 + slot;
    short8 a = *(const short8*)(pacc + (size_t)sidx * 16384 + row * 64 + d8 * 8);
#pragma unroll
    for (int k = 0; k < 8; ++k) acc[k] += frombf(a[k]);
    lsum += plrun[sidx * 256 + row];
  }
  float li = 1.0f / lsum;
  int b = bh >> 4, h = bh & 15;
  int m = b * 2048 + qt * 256 + row;
  int n = h * 64 + d8 * 8;
  short8 o;
#pragma unroll
  for (int k = 0; k < 8; ++k) o[k] = tobf(acc[k] * li);
  *(short8*)(attnb + (size_t)m * 1024 + n) = o;
}

// ---------- launch ----------
extern "C" void kernel_launch(void* const* d_in, const int* in_sizes, int n_in,
                              void* d_out, int out_size, void* d_ws, size_t ws_size,
                              hipStream_t stream) {
  const float* x    = (const float*)d_in[0];
  const float* Wqkv = (const float*)d_in[1];
  const float* bqkv = (const float*)d_in[2];
  const float* Wout = (const float*)d_in[3];
  const float* bout = (const float*)d_in[4];

  char* ws = (char*)d_ws;
  // Compact aliased layout, total 51,380,224 B (proven-safe R19-R23):
  //  [0, 33.55M)        pacc  (16.78M used: [512][256][64] bf16)
  //    [0, 8.39M)         xb     (gemm0-only; dead before attn_k writes pacc)
  //    [8.39M, 11.53M)    WqkvT  (gemm0-only)
  //    [11.53M, 11.80M)   cost   (gemm0-only)
  //    [11.80M, 12.06M)   sint   (gemm0-only)
  //  [33.55M, 35.65M)   WoutT (live prep_k -> gemm1)
  //  [35.65M, 48.23M)   qkvb  (gemm0 -> attn_k)
  //    [35.65M, 44.04M)   attnb (aliases qkvb: written by combine_k AFTER
  //                              qkvb's last read in attn_k; read by gemm1)
  //  [48.23M, 50.33M)   vTb   (gemm0 -> attn_k)
  //  [50.33M, 51.38M)   plrun [512][256] f32 = 512 KB used
  short* pacc  = (short*)(ws + 0);
  short* xb    = (short*)(ws + 0);
  short* WqkvT = (short*)(ws + 8388608);
  float* cost  = (float*)(ws + 11534336);
  float* sint  = (float*)(ws + 11796480);
  short* WoutT = (short*)(ws + 33554432);
  short* qkvb  = (short*)(ws + 35651584);
  short* attnb = (short*)(ws + 35651584);
  short* vTb   = (short*)(ws + 48234496);
  float* plrun = (float*)(ws + 50331648);

  prep_k<<<1920, 256, 0, stream>>>(x, xb, Wqkv, WqkvT, Wout, WoutT, cost, sint);
  gemm_k<0><<<768, 256, 0, stream>>>(xb, WqkvT, bqkv, (void*)qkvb, vTb, 4096, 1536, 1024, cost, sint);
  attn_k<<<256, 512, 0, stream>>>(qkvb, vTb, pacc, plrun);
  combine_k<<<2048, 256, 0, stream>>>(pacc, plrun, attnb);
  gemm_k<1><<<512, 256, 0, stream>>>(attnb, WoutT, bout, d_out, nullptr, 4096, 1024, 1024, cost, sint);
}

// Round 26
// 88.032 us; speedup vs baseline: 1.5717x; 1.0110x over previous
//
#include <hip/hip_runtime.h>
#include <hip/hip_bf16.h>

// ---------- types ----------
typedef __attribute__((ext_vector_type(8))) short short8;
typedef __attribute__((ext_vector_type(4))) float f32x4;

__device__ __forceinline__ short tobf(float f) {
  __hip_bfloat16 h = __float2bfloat16(f);
  return *reinterpret_cast<short*>(&h);
}
__device__ __forceinline__ float frombf(short s) {
  unsigned u = ((unsigned)(unsigned short)s) << 16;
  return __uint_as_float(u);
}

// XOR swizzle of the 16B-column index within a 128B LDS row (G4 / T2).
__device__ __forceinline__ int swz(int row) { return (row ^ (row >> 3)) & 7; }

#define GLDS16(gp, lp) __builtin_amdgcn_global_load_lds( \
    (__attribute__((address_space(1))) void*)(gp),       \
    (__attribute__((address_space(3))) void*)(lp), 16, 0, 0)

// raw transcendental: D = 2^S0 (1 inst; inputs bounded, -1e30 -> 0)
__device__ __forceinline__ float exp2raw(float x) {
  float r;
  asm("v_exp_f32 %0, %1" : "=v"(r) : "v"(x));
  return r;
}
// pack 2 f32 -> 2 bf16 in one dword (RNE, same as __float2bfloat16)
__device__ __forceinline__ unsigned cvtpk(float lo, float hi) {
  unsigned r;
  asm("v_cvt_pk_bf16_f32 %0, %1, %2" : "=v"(r) : "v"(lo), "v"(hi));
  return r;
}

// q pre-scale folded into QKV-GEMM epilogue: S = (q*alpha)·k is then in
// log2 domain with the 1/sqrt(64) attention scale included -> attn uses exp2.
#define QSCALE 0.18033688011112042f  // 0.125 * log2(e)

// ---------- fused prep kernel ----------
__global__ __launch_bounds__(256) void prep_k(
    const float* __restrict__ x, short* __restrict__ xb,
    const float* __restrict__ Wqkv, short* __restrict__ WqkvT,
    const float* __restrict__ Wout, short* __restrict__ WoutT,
    float* __restrict__ cost, float* __restrict__ sint) {
  __shared__ float t[64][65];
  const int bx = blockIdx.x, tid = threadIdx.x;
  if (bx < 1024) {
    int base = bx * 4096 + tid * 4;
#pragma unroll
    for (int rep = 0; rep < 4; ++rep) {
      int i = base + rep * 1024;
      float4 v = *(const float4*)(x + i);
      *(short4*)(xb + i) = make_short4(tobf(v.x), tobf(v.y), tobf(v.z), tobf(v.w));
    }
  } else if (bx < 1664) {
    const float* in;
    short* out;
    int C, bb;
    if (bx < 1408) { in = Wqkv; out = WqkvT; C = 1536; bb = bx - 1024; }
    else           { in = Wout; out = WoutT; C = 1024; bb = bx - 1408; }
    const int R = 1024;
    int nc = C >> 6;
    int br = bb / nc, bc = bb % nc;
    int lr = tid >> 6, lc = tid & 63;
#pragma unroll
    for (int j = 0; j < 16; ++j) {
      int r = j * 4 + lr;
      t[r][lc] = in[(size_t)(br * 64 + r) * C + bc * 64 + lc];
    }
    __syncthreads();
#pragma unroll
    for (int j = 0; j < 16; ++j) {
      int r = j * 4 + lr;
      out[(size_t)(bc * 64 + r) * R + br * 64 + lc] = tobf(t[lc][r]);
    }
  } else {
    int t2 = (bx - 1664) * 256 + tid;  // < 65536
    int s = t2 >> 5, f = t2 & 31;
    float inv = __expf(-(float)f * (logf(50000.0f) / 32.0f));
    float a = (float)s * inv;
    cost[t2] = cosf(a);
    sint[t2] = sinf(a);
  }
}

// ---------- GEMM: C[M][N] = A[M][K](bf16) * Bt[N][K](bf16)^T + bias ----------
// 128x64 tiles, DOUBLE-BUFFERED (R26): issue next K-tile's GLDS at iter top,
// compute current, vmcnt(0)+ONE barrier at bottom (loads had the whole MFMA
// span to land; prior reads of the target buffer retired at previous barrier).
// MODE 0: QKV proj; RoPE + q-prescale epilogue; q/k -> qkvb, v -> vT (fused
// transpose). MODE 1: f32 out.
template <int MODE>
__global__ __launch_bounds__(256) void gemm_k(
    const short* __restrict__ A, const short* __restrict__ Bt,
    const float* __restrict__ bias, void* __restrict__ Cout,
    short* __restrict__ vT,
    int M, int N, int K,
    const float* __restrict__ cost, const float* __restrict__ sint) {
  __shared__ short As[2][128 * 64];  // 32KB
  __shared__ short Bs[2][64 * 64];   // 16KB
  const int ntile = N >> 6;
  const int bm = blockIdx.x / ntile, bn = blockIdx.x % ntile;
  const int tid = threadIdx.x, w = tid >> 6, l = tid & 63;
  const int c = l & 15, g = l >> 4;
  const int m0 = bm * 128, n0 = bn * 64;

  // per-thread staging offsets (loop-invariant)
  const int jrow = l >> 3;
  const int jcol = l & 7;

  f32x4 acc[2][4] = {};

  // prologue: stage K-tile 0 into buffer 0
#pragma unroll
  for (int j = 0; j < 4; ++j) {
    int rb = j * 32 + w * 8;
    int row = rb + jrow;
    int colel = (jcol ^ swz(row)) * 8;
    GLDS16(A + (size_t)(m0 + row) * K + colel, &As[0][rb * 64]);
    if (j < 2) GLDS16(Bt + (size_t)(n0 + row) * K + colel, &Bs[0][rb * 64]);
  }
  asm volatile("s_waitcnt vmcnt(0)" ::: "memory");
  __builtin_amdgcn_s_barrier();
  __builtin_amdgcn_sched_barrier(0);

  const int niter = K >> 6;
  for (int it = 0; it < niter; ++it) {
    const int cur = it & 1, nxt = cur ^ 1;
    const int k0n = (it + 1) << 6;
    if (it + 1 < niter) {  // issue next tile at iter TOP (hides under MFMA)
#pragma unroll
      for (int j = 0; j < 4; ++j) {
        int rb = j * 32 + w * 8;
        int row = rb + jrow;
        int colel = (jcol ^ swz(row)) * 8;
        GLDS16(A + (size_t)(m0 + row) * K + k0n + colel, &As[nxt][rb * 64]);
        if (j < 2) GLDS16(Bt + (size_t)(n0 + row) * K + k0n + colel, &Bs[nxt][rb * 64]);
      }
    }
#pragma unroll
    for (int kk = 0; kk < 2; ++kk) {
      short8 af[2], bf[4];
#pragma unroll
      for (int mi = 0; mi < 2; ++mi) {
        int row = w * 32 + mi * 16 + c;
        af[mi] = *(const short8*)&As[cur][row * 64 + ((kk * 4 + g) ^ swz(row)) * 8];
      }
#pragma unroll
      for (int ni = 0; ni < 4; ++ni) {
        int row = ni * 16 + c;
        bf[ni] = *(const short8*)&Bs[cur][row * 64 + ((kk * 4 + g) ^ swz(row)) * 8];
      }
#pragma unroll
      for (int mi = 0; mi < 2; ++mi)
#pragma unroll
        for (int ni = 0; ni < 4; ++ni)
          acc[mi][ni] = __builtin_amdgcn_mfma_f32_16x16x32_bf16(af[mi], bf[ni], acc[mi][ni], 0, 0, 0);
    }
    asm volatile("s_waitcnt vmcnt(0)" ::: "memory");  // next tile landed
    __builtin_amdgcn_s_barrier();
    __builtin_amdgcn_sched_barrier(0);
  }

  if (MODE == 0 && n0 >= 1280) {
    // v region: write transposed directly to vT[b*4+hg][64 d][2048 s]
    const int hg = (n0 - 1280) >> 6;
#pragma unroll
    for (int mi = 0; mi < 2; ++mi) {
      int m0r = m0 + w * 32 + mi * 16 + g * 4;  // 4 consecutive rows
      int b = m0r >> 11, s = m0r & 2047;
#pragma unroll
      for (int ni = 0; ni < 4; ++ni) {
        int d = ni * 16 + c;
        float bs = bias[n0 + d];
        short4 o;
        o.x = tobf(acc[mi][ni][0] + bs);
        o.y = tobf(acc[mi][ni][1] + bs);
        o.z = tobf(acc[mi][ni][2] + bs);
        o.w = tobf(acc[mi][ni][3] + bs);
        *(short4*)&vT[(size_t)((b * 4 + hg) * 64 + d) * 2048 + s] = o;
      }
    }
    return;
  }

#pragma unroll
  for (int mi = 0; mi < 2; ++mi)
#pragma unroll
    for (int r = 0; r < 4; ++r) {
      int m = m0 + w * 32 + mi * 16 + g * 4 + r;
      int s = m & 2047;
#pragma unroll
      for (int ni = 0; ni < 4; ++ni) {
        int n = n0 + ni * 16 + c;
        float v = acc[mi][ni][r] + bias[n];
        if (MODE == 0) {
          // q or k region (n < 1280 guaranteed here): apply RoPE
          int d = n & 63, f = d & 31;
          float cs = cost[s * 32 + f], sn = sint[s * 32 + f];
          float partner = acc[mi][ni ^ 2][r] + bias[n ^ 32];
          v = (d < 32) ? (v * cs - partner * sn) : (v * cs + partner * sn);
          if (n < 1024) v *= QSCALE;  // q prescale (commutes with rotation)
          ((short*)Cout)[(size_t)m * N + n] = tobf(v);
        } else {
          ((float*)Cout)[(size_t)m * N + n] = v;
        }
      }
    }
}

// ---------- flash attention (causal, GQA): 2 K-TILES PER BARRIER ----------
// QBLK=256, 8 waves x 32 q-rows (2 sets of 16), grid 256 = 1 block/CU,
// pair (qtB=7-p, qtA=p) split in 2 halves of 18 tiles; SUPER-ITERS of 2
// cores per barrier span; 6-buffer rotation; counted vmcnt(4); lane-partial
// lrun; raw v_exp_f32; cvt_pk P-pack. (R25 structure, unchanged.)
__global__ __launch_bounds__(512) void attn_k(const short* __restrict__ qkv,
                                              const short* __restrict__ vT,
                                              short* __restrict__ pacc,
                                              float* __restrict__ plrun) {
  __shared__ short Ks6[6][64 * 64];  // 48KB
  __shared__ short Vt6[6][64 * 64];  // 48KB
  __shared__ short Ps[8][16 * 64];   // 16KB per-wave P tiles

  const int bx = blockIdx.x;
  const int bh = bx & 31;
  const int rest = bx >> 5;          // 0..7
  const int p = rest & 3;            // pair 0..3
  const int half = rest >> 2;        // 0 or 1
  const int qtB = 7 - p, qtA = p;
  const int sB = 32 - 4 * p;         // k-tiles in qtB's causal range (>= 20, even)
  const int start = half * 18;
  const int end = start + 18;
  const int b = bh >> 4, h = bh & 15, hg = h >> 2;
  const int tid = threadIdx.x, w = tid >> 6, l = tid & 63;
  const int c = l & 15, g = l >> 4;
  const size_t rowbase = (size_t)(b * 2048) * 1536;

  // staging: each wave stages 8 rows (1 GLDS16 per tile per thread)
  const int srow = w * 8 + (l >> 3);
  const int scol = ((l & 7) ^ swz(srow)) * 8;
  const size_t koff = (size_t)srow * 1536 + scol;
  const size_t voff = (size_t)srow * 2048 + scol;
  const int ldsoff = (w * 8) * 64;   // wave-uniform LDS base
  const short* kbase = qkv + rowbase + 1024 + hg * 64;
  const short* vbase_p = vT + (size_t)((b * 4 + hg) * 64) * 2048;

#define KTOF(i) (((i) < sB) ? (i) : ((i) - sB))

  // ---- prologue: issue tiles start..start+3 (segments have >= 18 tiles) ----
#pragma unroll
  for (int t = 0; t < 4; ++t) {
    int idx = start + t;
    int kt0 = KTOF(idx);
    int bf_ = idx % 6;
    GLDS16(kbase + (size_t)kt0 * 98304 + koff, &Ks6[bf_][ldsoff]);
    GLDS16(vbase_p + kt0 * 64 + voff, &Vt6[bf_][ldsoff]);
  }
  asm volatile("s_waitcnt vmcnt(4)" ::: "memory");  // tiles start,start+1 landed
  __builtin_amdgcn_s_barrier();
  __builtin_amdgcn_sched_barrier(0);

  f32x4 acco[2][4] = {};
  float lrun[2] = {0.f, 0.f};  // LANE-PARTIAL (own 16 k-slots); reduced at store
  short* Pw = &Ps[w][0];
  short8 aq[2][2];

  // Q fragments for qtB: q = qtB*256 + w*32 + set*16 + c
#pragma unroll
  for (int set = 0; set < 2; ++set)
#pragma unroll
    for (int kk = 0; kk < 2; ++kk)
      aq[set][kk] = *(const short8*)(qkv + rowbase +
          (size_t)(qtB * 256 + w * 32 + set * 16 + c) * 1536 + h * 64 + kk * 32 + g * 8);

// one k-tile core: QK -> mask -> exp -> pack -> PV (no sync; buffer TI%6)
#define CORE(qtc, TI)                                                           \
  {                                                                             \
    const int kt_ = KTOF(TI);                                                   \
    const int bf_ = (TI) % 6;                                                   \
    short8 bk[2][4];                                                            \
    _Pragma("unroll") for (int kk = 0; kk < 2; ++kk)                            \
      _Pragma("unroll") for (int nb = 0; nb < 4; ++nb) {                        \
        int row = nb * 16 + c;                                                  \
        bk[kk][nb] = *(const short8*)&Ks6[bf_][row * 64 + ((kk * 4 + g) ^ swz(row)) * 8]; \
      }                                                                         \
    f32x4 sfr[2][4] = {};                                                       \
    __builtin_amdgcn_s_setprio(1);                                              \
    _Pragma("unroll") for (int set = 0; set < 2; ++set)                         \
      _Pragma("unroll") for (int kk = 0; kk < 2; ++kk)                          \
        _Pragma("unroll") for (int nb = 0; nb < 4; ++nb)                        \
          sfr[set][nb] = __builtin_amdgcn_mfma_f32_16x16x32_bf16(               \
              bk[kk][nb], aq[set][kk], sfr[set][nb], 0, 0, 0);                  \
    __builtin_amdgcn_s_setprio(0);                                              \
    short8 bv[2][4];                                                            \
    _Pragma("unroll") for (int kk = 0; kk < 2; ++kk)                            \
      _Pragma("unroll") for (int nb = 0; nb < 4; ++nb) {                        \
        int row = nb * 16 + c;                                                  \
        bv[kk][nb] = *(const short8*)&Vt6[bf_][row * 64 + ((kk * 4 + g) ^ swz(row)) * 8]; \
      }                                                                         \
    if (kt_ >= 4 * (qtc)) {  /* tiles intersecting the diagonal band */         \
      _Pragma("unroll") for (int set = 0; set < 2; ++set) {                     \
        int qg = (qtc)*256 + w * 32 + set * 16 + c;                             \
        _Pragma("unroll") for (int nb = 0; nb < 4; ++nb)                        \
          _Pragma("unroll") for (int r = 0; r < 4; ++r)                         \
            if (kt_ * 64 + nb * 16 + g * 4 + r > qg) sfr[set][nb][r] = -1e30f;  \
      }                                                                         \
    }                                                                           \
    _Pragma("unroll") for (int set = 0; set < 2; ++set) {                       \
      float rsn[4];                                                             \
      _Pragma("unroll") for (int nb = 0; nb < 4; ++nb) {                        \
        float p0 = exp2raw(sfr[set][nb][0]);                                    \
        float p1 = exp2raw(sfr[set][nb][1]);                                    \
        float p2 = exp2raw(sfr[set][nb][2]);                                    \
        float p3 = exp2raw(sfr[set][nb][3]);                                    \
        sfr[set][nb][0] = p0; sfr[set][nb][1] = p1;                             \
        sfr[set][nb][2] = p2; sfr[set][nb][3] = p3;                             \
        rsn[nb] = (p0 + p1) + (p2 + p3);                                        \
      }                                                                         \
      lrun[set] += (rsn[0] + rsn[1]) + (rsn[2] + rsn[3]);                       \
      _Pragma("unroll") for (int nb = 0; nb < 4; ++nb) {                        \
        unsigned d0 = cvtpk(sfr[set][nb][0], sfr[set][nb][1]);                  \
        unsigned d1 = cvtpk(sfr[set][nb][2], sfr[set][nb][3]);                  \
        int pslot = (nb * 2 + (g >> 1)) ^ swz(c);                               \
        int2 pq2 = make_int2((int)d0, (int)d1);                                 \
        *(int2*)&Pw[c * 64 + pslot * 8 + (g & 1) * 4] = pq2;                    \
      }                                                                         \
      __builtin_amdgcn_s_setprio(1);                                            \
      _Pragma("unroll") for (int kk = 0; kk < 2; ++kk) {                        \
        short8 ap = *(const short8*)&Pw[c * 64 + (((kk * 4 + g) ^ swz(c)) * 8)];\
        _Pragma("unroll") for (int nb = 0; nb < 4; ++nb)                        \
          acco[set][nb] = __builtin_amdgcn_mfma_f32_16x16x32_bf16(              \
              ap, bv[kk][nb], acco[set][nb], 0, 0, 0);                          \
      }                                                                         \
      __builtin_amdgcn_s_setprio(0);                                            \
    }                                                                           \
  }

// super-iter: prefetch tiles i+4,i+5 (buffers i-2,i-1 mod 6: retired), then
// two cores, then counted-vmcnt barrier (newest 4 loads stay in flight)
#define SUPER(qtc)                                                              \
  {                                                                             \
    const bool pf_ = (i + 4 < end);                                             \
    if (pf_) {                                                                  \
      int ta = KTOF(i + 4), tb = KTOF(i + 5);                                   \
      int ba = (i + 4) % 6, bb2 = (i + 5) % 6;                                  \
      GLDS16(kbase + (size_t)ta * 98304 + koff, &Ks6[ba][ldsoff]);              \
      GLDS16(vbase_p + ta * 64 + voff, &Vt6[ba][ldsoff]);                       \
      GLDS16(kbase + (size_t)tb * 98304 + koff, &Ks6[bb2][ldsoff]);             \
      GLDS16(vbase_p + tb * 64 + voff, &Vt6[bb2][ldsoff]);                      \
    }                                                                           \
    CORE(qtc, i);                                                               \
    CORE(qtc, i + 1);                                                           \
    if (pf_) asm volatile("s_waitcnt vmcnt(4)" ::: "memory");                   \
    else     asm volatile("s_waitcnt vmcnt(0)" ::: "memory");                   \
    __builtin_amdgcn_s_barrier();                                               \
    __builtin_amdgcn_sched_barrier(0);                                          \
  }

#define STORE_PARTIAL(slot)                                                     \
  {                                                                             \
    int sidx = ((bh * 4 + p) * 2 + half) * 2 + (slot);                          \
    size_t pb = (size_t)sidx * 16384;                                           \
    _Pragma("unroll") for (int set = 0; set < 2; ++set) {                       \
      _Pragma("unroll") for (int nb = 0; nb < 4; ++nb)                          \
        _Pragma("unroll") for (int r = 0; r < 4; ++r) {                         \
          int row = w * 32 + set * 16 + g * 4 + r;                              \
          pacc[pb + row * 64 + nb * 16 + c] = tobf(acco[set][nb][r]);           \
          acco[set][nb][r] = 0.f;                                               \
        }                                                                       \
      float lr_ = lrun[set];                                                    \
      lr_ += __shfl_xor(lr_, 16, 64);                                           \
      lr_ += __shfl_xor(lr_, 32, 64);  /* full row sum over 4 g-lanes */        \
      if (g == 0) plrun[sidx * 256 + w * 32 + set * 16 + c] = lr_;              \
      lrun[set] = 0.f;                                                          \
    }                                                                           \
  }

  int i = start;
  const int endB = (end < sB) ? end : sB;  // segment lengths are even
  for (; i < endB; i += 2) SUPER(qtB);
  STORE_PARTIAL(0);

  // swap Q fragments to qtA (reuses aq registers; qtB frags dead)
#pragma unroll
  for (int set = 0; set < 2; ++set)
#pragma unroll
    for (int kk = 0; kk < 2; ++kk)
      aq[set][kk] = *(const short8*)(qkv + rowbase +
          (size_t)(qtA * 256 + w * 32 + set * 16 + c) * 1536 + h * 64 + kk * 32 + g * 8);

  for (; i < end; i += 2) SUPER(qtA);
  STORE_PARTIAL(1);

#undef CORE
#undef SUPER
#undef STORE_PARTIAL
#undef KTOF
}

// ---------- combine: sum 2 half-partials, normalize ----------
__global__ __launch_bounds__(256) void combine_k(const short* __restrict__ pacc,
                                                 const float* __restrict__ plrun,
                                                 short* __restrict__ attnb) {
  int e = blockIdx.x * 256 + threadIdx.x;  // 0..524287
  int d8 = e & 7;
  int t = e >> 3;
  int row = t & 255;                 // 0..255 within q-tile
  int t2 = t >> 8;
  int qt = t2 & 7;                   // q-tile of 256 rows
  int bh = t2 >> 3;
  int p = (qt < 7 - qt) ? qt : 7 - qt;
  int slot = (qt >= 4) ? 0 : 1;
  float acc[8] = {};
  float lsum = 0.f;
#pragma unroll
  for (int half = 0; half < 2; ++half) {
    int sidx = ((bh * 4 + p) * 2 + half) * 2 + slot;
    short8 a = *(const short8*)(pacc + (size_t)sidx * 16384 + row * 64 + d8 * 8);
#pragma unroll
    for (int k = 0; k < 8; ++k) acc[k] += frombf(a[k]);
    lsum += plrun[sidx * 256 + row];
  }
  float li = 1.0f / lsum;
  int b = bh >> 4, h = bh & 15;
  int m = b * 2048 + qt * 256 + row;
  int n = h * 64 + d8 * 8;
  short8 o;
#pragma unroll
  for (int k = 0; k < 8; ++k) o[k] = tobf(acc[k] * li);
  *(short8*)(attnb + (size_t)m * 1024 + n) = o;
}

// ---------- launch ----------
extern "C" void kernel_launch(void* const* d_in, const int* in_sizes, int n_in,
                              void* d_out, int out_size, void* d_ws, size_t ws_size,
                              hipStream_t stream) {
  const float* x    = (const float*)d_in[0];
  const float* Wqkv = (const float*)d_in[1];
  const float* bqkv = (const float*)d_in[2];
  const float* Wout = (const float*)d_in[3];
  const float* bout = (const float*)d_in[4];

  char* ws = (char*)d_ws;
  // Compact aliased layout, total 51,380,224 B (proven-safe R19-R25):
  //  [0, 33.55M)        pacc  (16.78M used: [512][256][64] bf16)
  //    [0, 8.39M)         xb     (gemm0-only; dead before attn_k writes pacc)
  //    [8.39M, 11.53M)    WqkvT  (gemm0-only)
  //    [11.53M, 11.80M)   cost   (gemm0-only)
  //    [11.80M, 12.06M)   sint   (gemm0-only)
  //  [33.55M, 35.65M)   WoutT (live prep_k -> gemm1)
  //  [35.65M, 48.23M)   qkvb  (gemm0 -> attn_k)
  //    [35.65M, 44.04M)   attnb (aliases qkvb: written by combine_k AFTER
  //                              qkvb's last read in attn_k; read by gemm1)
  //  [48.23M, 50.33M)   vTb   (gemm0 -> attn_k)
  //  [50.33M, 51.38M)   plrun [512][256] f32 = 512 KB used
  short* pacc  = (short*)(ws + 0);
  short* xb    = (short*)(ws + 0);
  short* WqkvT = (short*)(ws + 8388608);
  float* cost  = (float*)(ws + 11534336);
  float* sint  = (float*)(ws + 11796480);
  short* WoutT = (short*)(ws + 33554432);
  short* qkvb  = (short*)(ws + 35651584);
  short* attnb = (short*)(ws + 35651584);
  short* vTb   = (short*)(ws + 48234496);
  float* plrun = (float*)(ws + 50331648);

  prep_k<<<1920, 256, 0, stream>>>(x, xb, Wqkv, WqkvT, Wout, WoutT, cost, sint);
  gemm_k<0><<<768, 256, 0, stream>>>(xb, WqkvT, bqkv, (void*)qkvb, vTb, 4096, 1536, 1024, cost, sint);
  attn_k<<<256, 512, 0, stream>>>(qkvb, vTb, pacc, plrun);
  combine_k<<<2048, 256, 0, stream>>>(pacc, plrun, attnb);
  gemm_k<1><<<512, 256, 0, stream>>>(attnb, WoutT, bout, d_out, nullptr, 4096, 1024, 1024, cost, sint);
}

// Round 27
// 87.524 us; speedup vs baseline: 1.5808x; 1.0058x over previous
//
#include <hip/hip_runtime.h>
#include <hip/hip_bf16.h>

// ---------- types ----------
typedef __attribute__((ext_vector_type(8))) short short8;
typedef __attribute__((ext_vector_type(4))) float f32x4;

__device__ __forceinline__ short tobf(float f) {
  __hip_bfloat16 h = __float2bfloat16(f);
  return *reinterpret_cast<short*>(&h);
}
__device__ __forceinline__ float frombf(short s) {
  unsigned u = ((unsigned)(unsigned short)s) << 16;
  return __uint_as_float(u);
}

// XOR swizzle of the 16B-column index within a 128B LDS row (G4 / T2).
__device__ __forceinline__ int swz(int row) { return (row ^ (row >> 3)) & 7; }

#define GLDS16(gp, lp) __builtin_amdgcn_global_load_lds( \
    (__attribute__((address_space(1))) void*)(gp),       \
    (__attribute__((address_space(3))) void*)(lp), 16, 0, 0)

// raw transcendental: D = 2^S0 (1 inst; inputs bounded, -1e30 -> 0)
__device__ __forceinline__ float exp2raw(float x) {
  float r;
  asm("v_exp_f32 %0, %1" : "=v"(r) : "v"(x));
  return r;
}
// pack 2 f32 -> 2 bf16 in one dword (RNE, same as __float2bfloat16)
__device__ __forceinline__ unsigned cvtpk(float lo, float hi) {
  unsigned r;
  asm("v_cvt_pk_bf16_f32 %0, %1, %2" : "=v"(r) : "v"(lo), "v"(hi));
  return r;
}

// q pre-scale folded into QKV-GEMM epilogue: S = (q*alpha)·k is then in
// log2 domain with the 1/sqrt(64) attention scale included -> attn uses exp2.
#define QSCALE 0.18033688011112042f  // 0.125 * log2(e)

// ---------- fused prep kernel ----------
__global__ __launch_bounds__(256) void prep_k(
    const float* __restrict__ x, short* __restrict__ xb,
    const float* __restrict__ Wqkv, short* __restrict__ WqkvT,
    const float* __restrict__ Wout, short* __restrict__ WoutT,
    float* __restrict__ cost, float* __restrict__ sint) {
  __shared__ float t[64][65];
  const int bx = blockIdx.x, tid = threadIdx.x;
  if (bx < 1024) {
    int base = bx * 4096 + tid * 4;
#pragma unroll
    for (int rep = 0; rep < 4; ++rep) {
      int i = base + rep * 1024;
      float4 v = *(const float4*)(x + i);
      *(short4*)(xb + i) = make_short4(tobf(v.x), tobf(v.y), tobf(v.z), tobf(v.w));
    }
  } else if (bx < 1664) {
    const float* in;
    short* out;
    int C, bb;
    if (bx < 1408) { in = Wqkv; out = WqkvT; C = 1536; bb = bx - 1024; }
    else           { in = Wout; out = WoutT; C = 1024; bb = bx - 1408; }
    const int R = 1024;
    int nc = C >> 6;
    int br = bb / nc, bc = bb % nc;
    int lr = tid >> 6, lc = tid & 63;
#pragma unroll
    for (int j = 0; j < 16; ++j) {
      int r = j * 4 + lr;
      t[r][lc] = in[(size_t)(br * 64 + r) * C + bc * 64 + lc];
    }
    __syncthreads();
#pragma unroll
    for (int j = 0; j < 16; ++j) {
      int r = j * 4 + lr;
      out[(size_t)(bc * 64 + r) * R + br * 64 + lc] = tobf(t[lc][r]);
    }
  } else {
    int t2 = (bx - 1664) * 256 + tid;  // < 65536
    int s = t2 >> 5, f = t2 & 31;
    float inv = __expf(-(float)f * (logf(50000.0f) / 32.0f));
    float a = (float)s * inv;
    cost[t2] = cosf(a);
    sint[t2] = sinf(a);
  }
}

// ---------- GEMM: C[M][N] = A[M][K](bf16) * Bt[N][K](bf16)^T + bias ----------
// 128x64 tiles, DOUBLE-BUFFERED: issue next K-tile's GLDS at iter top,
// compute current, vmcnt(0)+ONE barrier at bottom. MODE 0: QKV proj with
// RoPE + q-prescale epilogue; q/k -> qkvb, v -> vT (fused transpose).
// MODE 1: f32 out.
template <int MODE>
__global__ __launch_bounds__(256) void gemm_k(
    const short* __restrict__ A, const short* __restrict__ Bt,
    const float* __restrict__ bias, void* __restrict__ Cout,
    short* __restrict__ vT,
    int M, int N, int K,
    const float* __restrict__ cost, const float* __restrict__ sint) {
  __shared__ short As[2][128 * 64];  // 32KB
  __shared__ short Bs[2][64 * 64];   // 16KB
  const int ntile = N >> 6;
  const int bm = blockIdx.x / ntile, bn = blockIdx.x % ntile;
  const int tid = threadIdx.x, w = tid >> 6, l = tid & 63;
  const int c = l & 15, g = l >> 4;
  const int m0 = bm * 128, n0 = bn * 64;

  // per-thread staging offsets (loop-invariant)
  const int jrow = l >> 3;
  const int jcol = l & 7;

  f32x4 acc[2][4] = {};

  // prologue: stage K-tile 0 into buffer 0
#pragma unroll
  for (int j = 0; j < 4; ++j) {
    int rb = j * 32 + w * 8;
    int row = rb + jrow;
    int colel = (jcol ^ swz(row)) * 8;
    GLDS16(A + (size_t)(m0 + row) * K + colel, &As[0][rb * 64]);
    if (j < 2) GLDS16(Bt + (size_t)(n0 + row) * K + colel, &Bs[0][rb * 64]);
  }
  asm volatile("s_waitcnt vmcnt(0)" ::: "memory");
  __builtin_amdgcn_s_barrier();
  __builtin_amdgcn_sched_barrier(0);

  const int niter = K >> 6;
  for (int it = 0; it < niter; ++it) {
    const int cur = it & 1, nxt = cur ^ 1;
    const int k0n = (it + 1) << 6;
    if (it + 1 < niter) {  // issue next tile at iter TOP (hides under MFMA)
#pragma unroll
      for (int j = 0; j < 4; ++j) {
        int rb = j * 32 + w * 8;
        int row = rb + jrow;
        int colel = (jcol ^ swz(row)) * 8;
        GLDS16(A + (size_t)(m0 + row) * K + k0n + colel, &As[nxt][rb * 64]);
        if (j < 2) GLDS16(Bt + (size_t)(n0 + row) * K + k0n + colel, &Bs[nxt][rb * 64]);
      }
    }
#pragma unroll
    for (int kk = 0; kk < 2; ++kk) {
      short8 af[2], bf[4];
#pragma unroll
      for (int mi = 0; mi < 2; ++mi) {
        int row = w * 32 + mi * 16 + c;
        af[mi] = *(const short8*)&As[cur][row * 64 + ((kk * 4 + g) ^ swz(row)) * 8];
      }
#pragma unroll
      for (int ni = 0; ni < 4; ++ni) {
        int row = ni * 16 + c;
        bf[ni] = *(const short8*)&Bs[cur][row * 64 + ((kk * 4 + g) ^ swz(row)) * 8];
      }
#pragma unroll
      for (int mi = 0; mi < 2; ++mi)
#pragma unroll
        for (int ni = 0; ni < 4; ++ni)
          acc[mi][ni] = __builtin_amdgcn_mfma_f32_16x16x32_bf16(af[mi], bf[ni], acc[mi][ni], 0, 0, 0);
    }
    asm volatile("s_waitcnt vmcnt(0)" ::: "memory");  // next tile landed
    __builtin_amdgcn_s_barrier();
    __builtin_amdgcn_sched_barrier(0);
  }

  if (MODE == 0 && n0 >= 1280) {
    // v region: write transposed directly to vT[b*4+hg][64 d][2048 s]
    const int hg = (n0 - 1280) >> 6;
#pragma unroll
    for (int mi = 0; mi < 2; ++mi) {
      int m0r = m0 + w * 32 + mi * 16 + g * 4;  // 4 consecutive rows
      int b = m0r >> 11, s = m0r & 2047;
#pragma unroll
      for (int ni = 0; ni < 4; ++ni) {
        int d = ni * 16 + c;
        float bs = bias[n0 + d];
        short4 o;
        o.x = tobf(acc[mi][ni][0] + bs);
        o.y = tobf(acc[mi][ni][1] + bs);
        o.z = tobf(acc[mi][ni][2] + bs);
        o.w = tobf(acc[mi][ni][3] + bs);
        *(short4*)&vT[(size_t)((b * 4 + hg) * 64 + d) * 2048 + s] = o;
      }
    }
    return;
  }

#pragma unroll
  for (int mi = 0; mi < 2; ++mi)
#pragma unroll
    for (int r = 0; r < 4; ++r) {
      int m = m0 + w * 32 + mi * 16 + g * 4 + r;
      int s = m & 2047;
#pragma unroll
      for (int ni = 0; ni < 4; ++ni) {
        int n = n0 + ni * 16 + c;
        float v = acc[mi][ni][r] + bias[n];
        if (MODE == 0) {
          // q or k region (n < 1280 guaranteed here): apply RoPE
          int d = n & 63, f = d & 31;
          float cs = cost[s * 32 + f], sn = sint[s * 32 + f];
          float partner = acc[mi][ni ^ 2][r] + bias[n ^ 32];
          v = (d < 32) ? (v * cs - partner * sn) : (v * cs + partner * sn);
          if (n < 1024) v *= QSCALE;  // q prescale (commutes with rotation)
          ((short*)Cout)[(size_t)m * N + n] = tobf(v);
        } else {
          ((float*)Cout)[(size_t)m * N + n] = v;
        }
      }
    }
}

// ---------- flash attention (causal, GQA): 2 K-TILES PER BARRIER ----------
// QBLK=256, 8 waves x 32 q-rows (2 sets of 16), grid 256 = 1 block/CU,
// pair (qtB=7-p, qtA=p) split in 2 halves of 18 tiles; SUPER-ITERS of 2
// cores per barrier span; 6-buffer rotation; counted vmcnt(4); lane-partial
// lrun; raw v_exp_f32; cvt_pk P-pack. R27: BOTH halves' Q fragments loaded
// up front (removes the exposed global-load chain at the qtB->qtA boundary;
// +16 VGPR, well under the R24 spill cliff).
__global__ __launch_bounds__(512) void attn_k(const short* __restrict__ qkv,
                                              const short* __restrict__ vT,
                                              short* __restrict__ pacc,
                                              float* __restrict__ plrun) {
  __shared__ short Ks6[6][64 * 64];  // 48KB
  __shared__ short Vt6[6][64 * 64];  // 48KB
  __shared__ short Ps[8][16 * 64];   // 16KB per-wave P tiles

  const int bx = blockIdx.x;
  const int bh = bx & 31;
  const int rest = bx >> 5;          // 0..7
  const int p = rest & 3;            // pair 0..3
  const int half = rest >> 2;        // 0 or 1
  const int qtB = 7 - p, qtA = p;
  const int sB = 32 - 4 * p;         // k-tiles in qtB's causal range (>= 20, even)
  const int start = half * 18;
  const int end = start + 18;
  const int b = bh >> 4, h = bh & 15, hg = h >> 2;
  const int tid = threadIdx.x, w = tid >> 6, l = tid & 63;
  const int c = l & 15, g = l >> 4;
  const size_t rowbase = (size_t)(b * 2048) * 1536;

  // staging: each wave stages 8 rows (1 GLDS16 per tile per thread)
  const int srow = w * 8 + (l >> 3);
  const int scol = ((l & 7) ^ swz(srow)) * 8;
  const size_t koff = (size_t)srow * 1536 + scol;
  const size_t voff = (size_t)srow * 2048 + scol;
  const int ldsoff = (w * 8) * 64;   // wave-uniform LDS base
  const short* kbase = qkv + rowbase + 1024 + hg * 64;
  const short* vbase_p = vT + (size_t)((b * 4 + hg) * 64) * 2048;

#define KTOF(i) (((i) < sB) ? (i) : ((i) - sB))

  // ---- prologue: issue tiles start..start+3 (segments have >= 18 tiles) ----
#pragma unroll
  for (int t = 0; t < 4; ++t) {
    int idx = start + t;
    int kt0 = KTOF(idx);
    int bf_ = idx % 6;
    GLDS16(kbase + (size_t)kt0 * 98304 + koff, &Ks6[bf_][ldsoff]);
    GLDS16(vbase_p + kt0 * 64 + voff, &Vt6[bf_][ldsoff]);
  }

  // Q fragments for BOTH q-tiles up front (latency hidden under prologue)
  short8 aqB[2][2], aqA[2][2];
#pragma unroll
  for (int set = 0; set < 2; ++set)
#pragma unroll
    for (int kk = 0; kk < 2; ++kk) {
      aqB[set][kk] = *(const short8*)(qkv + rowbase +
          (size_t)(qtB * 256 + w * 32 + set * 16 + c) * 1536 + h * 64 + kk * 32 + g * 8);
      aqA[set][kk] = *(const short8*)(qkv + rowbase +
          (size_t)(qtA * 256 + w * 32 + set * 16 + c) * 1536 + h * 64 + kk * 32 + g * 8);
    }

  asm volatile("s_waitcnt vmcnt(4)" ::: "memory");  // tiles start,start+1 landed
  __builtin_amdgcn_s_barrier();
  __builtin_amdgcn_sched_barrier(0);

  f32x4 acco[2][4] = {};
  float lrun[2] = {0.f, 0.f};  // LANE-PARTIAL (own 16 k-slots); reduced at store
  short* Pw = &Ps[w][0];

// one k-tile core: QK -> mask -> exp -> pack -> PV (no sync; buffer TI%6)
#define CORE(qtc, AQ, TI)                                                       \
  {                                                                             \
    const int kt_ = KTOF(TI);                                                   \
    const int bf_ = (TI) % 6;                                                   \
    short8 bk[2][4];                                                            \
    _Pragma("unroll") for (int kk = 0; kk < 2; ++kk)                            \
      _Pragma("unroll") for (int nb = 0; nb < 4; ++nb) {                        \
        int row = nb * 16 + c;                                                  \
        bk[kk][nb] = *(const short8*)&Ks6[bf_][row * 64 + ((kk * 4 + g) ^ swz(row)) * 8]; \
      }                                                                         \
    f32x4 sfr[2][4] = {};                                                       \
    __builtin_amdgcn_s_setprio(1);                                              \
    _Pragma("unroll") for (int set = 0; set < 2; ++set)                         \
      _Pragma("unroll") for (int kk = 0; kk < 2; ++kk)                          \
        _Pragma("unroll") for (int nb = 0; nb < 4; ++nb)                        \
          sfr[set][nb] = __builtin_amdgcn_mfma_f32_16x16x32_bf16(               \
              bk[kk][nb], AQ[set][kk], sfr[set][nb], 0, 0, 0);                  \
    __builtin_amdgcn_s_setprio(0);                                              \
    short8 bv[2][4];                                                            \
    _Pragma("unroll") for (int kk = 0; kk < 2; ++kk)                            \
      _Pragma("unroll") for (int nb = 0; nb < 4; ++nb) {                        \
        int row = nb * 16 + c;                                                  \
        bv[kk][nb] = *(const short8*)&Vt6[bf_][row * 64 + ((kk * 4 + g) ^ swz(row)) * 8]; \
      }                                                                         \
    if (kt_ >= 4 * (qtc)) {  /* tiles intersecting the diagonal band */         \
      _Pragma("unroll") for (int set = 0; set < 2; ++set) {                     \
        int qg = (qtc)*256 + w * 32 + set * 16 + c;                             \
        _Pragma("unroll") for (int nb = 0; nb < 4; ++nb)                        \
          _Pragma("unroll") for (int r = 0; r < 4; ++r)                         \
            if (kt_ * 64 + nb * 16 + g * 4 + r > qg) sfr[set][nb][r] = -1e30f;  \
      }                                                                         \
    }                                                                           \
    _Pragma("unroll") for (int set = 0; set < 2; ++set) {                       \
      float rsn[4];                                                             \
      _Pragma("unroll") for (int nb = 0; nb < 4; ++nb) {                        \
        float p0 = exp2raw(sfr[set][nb][0]);                                    \
        float p1 = exp2raw(sfr[set][nb][1]);                                    \
        float p2 = exp2raw(sfr[set][nb][2]);                                    \
        float p3 = exp2raw(sfr[set][nb][3]);                                    \
        sfr[set][nb][0] = p0; sfr[set][nb][1] = p1;                             \
        sfr[set][nb][2] = p2; sfr[set][nb][3] = p3;                             \
        rsn[nb] = (p0 + p1) + (p2 + p3);                                        \
      }                                                                         \
      lrun[set] += (rsn[0] + rsn[1]) + (rsn[2] + rsn[3]);                       \
      _Pragma("unroll") for (int nb = 0; nb < 4; ++nb) {                        \
        unsigned d0 = cvtpk(sfr[set][nb][0], sfr[set][nb][1]);                  \
        unsigned d1 = cvtpk(sfr[set][nb][2], sfr[set][nb][3]);                  \
        int pslot = (nb * 2 + (g >> 1)) ^ swz(c);                               \
        int2 pq2 = make_int2((int)d0, (int)d1);                                 \
        *(int2*)&Pw[c * 64 + pslot * 8 + (g & 1) * 4] = pq2;                    \
      }                                                                         \
      __builtin_amdgcn_s_setprio(1);                                            \
      _Pragma("unroll") for (int kk = 0; kk < 2; ++kk) {                        \
        short8 ap = *(const short8*)&Pw[c * 64 + (((kk * 4 + g) ^ swz(c)) * 8)];\
        _Pragma("unroll") for (int nb = 0; nb < 4; ++nb)                        \
          acco[set][nb] = __builtin_amdgcn_mfma_f32_16x16x32_bf16(              \
              ap, bv[kk][nb], acco[set][nb], 0, 0, 0);                          \
      }                                                                         \
      __builtin_amdgcn_s_setprio(0);                                            \
    }                                                                           \
  }

// super-iter: prefetch tiles i+4,i+5 (buffers i-2,i-1 mod 6: retired), then
// two cores, then counted-vmcnt barrier (newest 4 loads stay in flight)
#define SUPER(qtc, AQ)                                                          \
  {                                                                             \
    const bool pf_ = (i + 4 < end);                                             \
    if (pf_) {                                                                  \
      int ta = KTOF(i + 4), tb = KTOF(i + 5);                                   \
      int ba = (i + 4) % 6, bb2 = (i + 5) % 6;                                  \
      GLDS16(kbase + (size_t)ta * 98304 + koff, &Ks6[ba][ldsoff]);              \
      GLDS16(vbase_p + ta * 64 + voff, &Vt6[ba][ldsoff]);                       \
      GLDS16(kbase + (size_t)tb * 98304 + koff, &Ks6[bb2][ldsoff]);             \
      GLDS16(vbase_p + tb * 64 + voff, &Vt6[bb2][ldsoff]);                      \
    }                                                                           \
    CORE(qtc, AQ, i);                                                           \
    CORE(qtc, AQ, i + 1);                                                       \
    if (pf_) asm volatile("s_waitcnt vmcnt(4)" ::: "memory");                   \
    else     asm volatile("s_waitcnt vmcnt(0)" ::: "memory");                   \
    __builtin_amdgcn_s_barrier();                                               \
    __builtin_amdgcn_sched_barrier(0);                                          \
  }

#define STORE_PARTIAL(slot)                                                     \
  {                                                                             \
    int sidx = ((bh * 4 + p) * 2 + half) * 2 + (slot);                          \
    size_t pb = (size_t)sidx * 16384;                                           \
    _Pragma("unroll") for (int set = 0; set < 2; ++set) {                       \
      _Pragma("unroll") for (int nb = 0; nb < 4; ++nb)                          \
        _Pragma("unroll") for (int r = 0; r < 4; ++r) {                         \
          int row = w * 32 + set * 16 + g * 4 + r;                              \
          pacc[pb + row * 64 + nb * 16 + c] = tobf(acco[set][nb][r]);           \
          acco[set][nb][r] = 0.f;                                               \
        }                                                                       \
      float lr_ = lrun[set];                                                    \
      lr_ += __shfl_xor(lr_, 16, 64);                                           \
      lr_ += __shfl_xor(lr_, 32, 64);  /* full row sum over 4 g-lanes */        \
      if (g == 0) plrun[sidx * 256 + w * 32 + set * 16 + c] = lr_;              \
      lrun[set] = 0.f;                                                          \
    }                                                                           \
  }

  int i = start;
  const int endB = (end < sB) ? end : sB;  // segment lengths are even
  for (; i < endB; i += 2) SUPER(qtB, aqB);
  STORE_PARTIAL(0);

  for (; i < end; i += 2) SUPER(qtA, aqA);
  STORE_PARTIAL(1);

#undef CORE
#undef SUPER
#undef STORE_PARTIAL
#undef KTOF
}

// ---------- combine: sum 2 half-partials, normalize ----------
__global__ __launch_bounds__(256) void combine_k(const short* __restrict__ pacc,
                                                 const float* __restrict__ plrun,
                                                 short* __restrict__ attnb) {
  int e = blockIdx.x * 256 + threadIdx.x;  // 0..524287
  int d8 = e & 7;
  int t = e >> 3;
  int row = t & 255;                 // 0..255 within q-tile
  int t2 = t >> 8;
  int qt = t2 & 7;                   // q-tile of 256 rows
  int bh = t2 >> 3;
  int p = (qt < 7 - qt) ? qt : 7 - qt;
  int slot = (qt >= 4) ? 0 : 1;
  float acc[8] = {};
  float lsum = 0.f;
#pragma unroll
  for (int half = 0; half < 2; ++half) {
    int sidx = ((bh * 4 + p) * 2 + half) * 2 + slot;
    short8 a = *(const short8*)(pacc + (size_t)sidx * 16384 + row * 64 + d8 * 8);
#pragma unroll
    for (int k = 0; k < 8; ++k) acc[k] += frombf(a[k]);
    lsum += plrun[sidx * 256 + row];
  }
  float li = 1.0f / lsum;
  int b = bh >> 4, h = bh & 15;
  int m = b * 2048 + qt * 256 + row;
  int n = h * 64 + d8 * 8;
  short8 o;
#pragma unroll
  for (int k = 0; k < 8; ++k) o[k] = tobf(acc[k] * li);
  *(short8*)(attnb + (size_t)m * 1024 + n) = o;
}

// ---------- launch ----------
extern "C" void kernel_launch(void* const* d_in, const int* in_sizes, int n_in,
                              void* d_out, int out_size, void* d_ws, size_t ws_size,
                              hipStream_t stream) {
  const float* x    = (const float*)d_in[0];
  const float* Wqkv = (const float*)d_in[1];
  const float* bqkv = (const float*)d_in[2];
  const float* Wout = (const float*)d_in[3];
  const float* bout = (const float*)d_in[4];

  char* ws = (char*)d_ws;
  // Compact aliased layout, total 51,380,224 B (proven-safe R19-R26):
  //  [0, 33.55M)        pacc  (16.78M used: [512][256][64] bf16)
  //    [0, 8.39M)         xb     (gemm0-only; dead before attn_k writes pacc)
  //    [8.39M, 11.53M)    WqkvT  (gemm0-only)
  //    [11.53M, 11.80M)   cost   (gemm0-only)
  //    [11.80M, 12.06M)   sint   (gemm0-only)
  //  [33.55M, 35.65M)   WoutT (live prep_k -> gemm1)
  //  [35.65M, 48.23M)   qkvb  (gemm0 -> attn_k)
  //    [35.65M, 44.04M)   attnb (aliases qkvb: written by combine_k AFTER
  //                              qkvb's last read in attn_k; read by gemm1)
  //  [48.23M, 50.33M)   vTb   (gemm0 -> attn_k)
  //  [50.33M, 51.38M)   plrun [512][256] f32 = 512 KB used
  short* pacc  = (short*)(ws + 0);
  short* xb    = (short*)(ws + 0);
  short* WqkvT = (short*)(ws + 8388608);
  float* cost  = (float*)(ws + 11534336);
  float* sint  = (float*)(ws + 11796480);
  short* WoutT = (short*)(ws + 33554432);
  short* qkvb  = (short*)(ws + 35651584);
  short* attnb = (short*)(ws + 35651584);
  short* vTb   = (short*)(ws + 48234496);
  float* plrun = (float*)(ws + 50331648);

  prep_k<<<1920, 256, 0, stream>>>(x, xb, Wqkv, WqkvT, Wout, WoutT, cost, sint);
  gemm_k<0><<<768, 256, 0, stream>>>(xb, WqkvT, bqkv, (void*)qkvb, vTb, 4096, 1536, 1024, cost, sint);
  attn_k<<<256, 512, 0, stream>>>(qkvb, vTb, pacc, plrun);
  combine_k<<<2048, 256, 0, stream>>>(pacc, plrun, attnb);
  gemm_k<1><<<512, 256, 0, stream>>>(attnb, WoutT, bout, d_out, nullptr, 4096, 1024, 1024, cost, sint);
}